// Round 1
// baseline (122.232 us; speedup 1.0000x reference)
//
#include <hip/hip_runtime.h>

#define NUM_BINS 256
#define HW4 65536                 // 512*512/4 float4 per plane
#define PLANES 16                 // batch
#define GROUP_F4 (PLANES * HW4)   // 1,048,576 float4 per (img, channel)
#define BLOCKS_PER_GROUP 256
#define THREADS 256
#define NCOPY 4                   // one LDS histogram copy per wave

// ---------------------------------------------------------------------------
// Kernel 1: per-(image,channel) histograms with LDS privatization.
// Each block owns one (img, channel) group -> channel is block-uniform.
// ---------------------------------------------------------------------------
__global__ __launch_bounds__(THREADS) void hist_kernel(
    const float* __restrict__ img1,
    const float* __restrict__ img2,
    unsigned int* __restrict__ hist /* [2][3][256] */) {

    __shared__ unsigned int lh[NCOPY][NUM_BINS];
    const int t = threadIdx.x;
    #pragma unroll
    for (int i = t; i < NCOPY * NUM_BINS; i += THREADS)
        ((unsigned int*)lh)[i] = 0u;
    __syncthreads();

    const int gid = blockIdx.x;
    const int group = gid / BLOCKS_PER_GROUP;        // 0..5 = im*3 + c
    const int blk = gid - group * BLOCKS_PER_GROUP;
    const int im = group / 3;
    const int c = group - im * 3;
    const float4* __restrict__ src =
        (const float4*)(im == 0 ? img1 : img2);
    unsigned int* lhw = lh[t >> 6];                  // per-wave copy

    // grid-stride over the group's 1M float4s; 16 iterations/thread
    for (int k = blk * THREADS + t; k < GROUP_F4;
         k += BLOCKS_PER_GROUP * THREADS) {
        const int b = k >> 16;            // plane (batch) index
        const int j = k & (HW4 - 1);      // offset within plane
        const float4 v = src[(b * 3 + c) * HW4 + j];
        const float xs[4] = {v.x, v.y, v.z, v.w};
        #pragma unroll
        for (int e = 0; e < 4; ++e) {
            const float x = xs[e];
            // torch.histc semantics: ignore outside [0,1]; x==1 -> last bin
            if (x >= 0.0f && x <= 1.0f) {
                int bi = (int)(x * 256.0f);   // == floor for x >= 0
                bi = bi > (NUM_BINS - 1) ? (NUM_BINS - 1) : bi;
                atomicAdd(&lhw[bi], 1u);
            }
        }
    }
    __syncthreads();

    // flush: thread t owns bin t
    const unsigned int s = lh[0][t] + lh[1][t] + lh[2][t] + lh[3][t];
    if (s) atomicAdd(&hist[group * NUM_BINS + t], s);
}

// ---------------------------------------------------------------------------
// Kernel 2: normalize, cumsum, sum |cdf1 - cdf2|, /3. One block, 256 threads.
// ---------------------------------------------------------------------------
__global__ __launch_bounds__(NUM_BINS) void finalize_kernel(
    const unsigned int* __restrict__ hist, float* __restrict__ out) {

    __shared__ float b1[NUM_BINS];
    __shared__ float b2[NUM_BINS];
    __shared__ float red[NUM_BINS / 64];

    const int t = threadIdx.x;
    float acc = 0.0f;

    for (int c = 0; c < 3; ++c) {
        const float f1 = (float)hist[c * NUM_BINS + t];
        const float f2 = (float)hist[(3 + c) * NUM_BINS + t];
        b1[t] = f1;
        b2[t] = f2;
        __syncthreads();
        // Hillis-Steele inclusive scan, 8 steps
        for (int off = 1; off < NUM_BINS; off <<= 1) {
            float a1 = 0.0f, a2 = 0.0f;
            if (t >= off) { a1 = b1[t - off]; a2 = b2[t - off]; }
            __syncthreads();
            b1[t] += a1;
            b2[t] += a2;
            __syncthreads();
        }
        const float s1 = b1[NUM_BINS - 1];   // total valid count, channel c
        const float s2 = b2[NUM_BINS - 1];
        acc += fabsf(b1[t] / s1 - b2[t] / s2);
        __syncthreads();   // protect b1/b2 reuse next channel
    }

    // block reduction: wave64 shuffle then LDS
    #pragma unroll
    for (int off = 32; off > 0; off >>= 1)
        acc += __shfl_down(acc, off, 64);
    if ((t & 63) == 0) red[t >> 6] = acc;
    __syncthreads();
    if (t == 0)
        out[0] = (red[0] + red[1] + red[2] + red[3]) * (1.0f / 3.0f);
}

// ---------------------------------------------------------------------------
extern "C" void kernel_launch(void* const* d_in, const int* in_sizes, int n_in,
                              void* d_out, int out_size, void* d_ws,
                              size_t ws_size, hipStream_t stream) {
    const float* img1 = (const float*)d_in[0];
    const float* img2 = (const float*)d_in[1];
    float* out = (float*)d_out;
    unsigned int* hist = (unsigned int*)d_ws;   // [2][3][256] uint32

    // d_ws is poisoned to 0xAA before every launch -> zero it every call
    hipMemsetAsync(hist, 0, 6 * NUM_BINS * sizeof(unsigned int), stream);

    hist_kernel<<<6 * BLOCKS_PER_GROUP, THREADS, 0, stream>>>(img1, img2, hist);
    finalize_kernel<<<1, NUM_BINS, 0, stream>>>(hist, out);
}